// Round 11
// baseline (382.722 us; speedup 1.0000x reference)
//
#include <hip/hip_runtime.h>
#include <stdint.h>

#define HW 16384
#define CDIM 768
#define EPSF 1e-8f

typedef float f32x4  __attribute__((ext_vector_type(4)));
typedef float f32x16 __attribute__((ext_vector_type(16)));
typedef int   i32x8  __attribute__((ext_vector_type(8)));
typedef uint32_t u32x4 __attribute__((ext_vector_type(4)));

__device__ inline void async16(const void* g, void* l) {
    __builtin_amdgcn_global_load_lds(
        (const __attribute__((address_space(1))) uint32_t*)g,
        (__attribute__((address_space(3))) uint32_t*)l, 16, 0, 0);
}

__device__ inline uint32_t pk4_fp8(float v0, float v1, float v2, float v3) {
    uint32_t r = __builtin_amdgcn_cvt_pk_fp8_f32(v0, v1, 0, false);
    r = __builtin_amdgcn_cvt_pk_fp8_f32(v2, v3, r, true);
    return r;   // bytes [v0,v1,v2,v3] little-endian
}

// ---- Kernel 1: strip transpose [C][HW] fp32 -> [HW][C] fp8 + sum-sq ----
// Round 19: THREE transpose variants (r7 atomics, r9 serial-strip, r10
// partials+fold) all landed ~99us non-GEMM. Common untested factor: the
// fp8 STORE pattern -- 4 B/lane into 64-B-per-row segments (c-blocked
// grid owns only 64 B of each 768-B row) = 4 scattered 64-B transactions
// per wave-store + partial-line writebacks. Fix: strip structure.
// Block = 32 spatial x FULL 768 channels; fp8 words accumulate in a
// 24 KB LDS outT; the strip's output is ONE CONTIGUOUS 24 KB range of
// the [HW][C] matrix -> dumped as 6 passes of perfect 4-KB dwordx4
// bursts. Sum-sq in registers across the c-loop (no atomics, no scratch,
// no fold kernel). Reads stay coalesced (128-B segments/row).
// LDS 33 KB -> 4 blocks/CU, 16 waves/CU. Grid 512 x 2.
// z=0: a (scale x16), z=1: b (scale x8 + invdb emitted directly).
__global__ void __launch_bounds__(256)
transpose_fp8_strip(const float* __restrict__ a, const float* __restrict__ b,
                    uint8_t* __restrict__ at8, uint8_t* __restrict__ bn8,
                    float* __restrict__ sumsq_a, float* __restrict__ sumsq_b,
                    float* __restrict__ invdb) {
    const int z = blockIdx.z;
    const float* src = z ? b : a;
    uint8_t* dst = z ? bn8 : at8;
    float* sums = z ? sumsq_b : sumsq_a;
    const float mult = z ? 8.0f : 16.0f;

    __shared__ float tile[64][33];        // [channel][spatial 32], +1 pad
    __shared__ uint32_t outT[32 * 192];   // [spatial 32][768 B as dwords]

    const int s0 = blockIdx.x * 32;
    const int t = threadIdx.x;
    const int l8 = t & 7;                 // 8 lanes x f32x4 = 32 floats/row
    const int sl = t >> 3;                // 0..31 spatial row (compute phase)

    float ss = 0.0f;                      // per-thread sum-sq partial

#pragma unroll 1
    for (int cb = 0; cb < 12; ++cb) {
        const int c0 = cb * 64;
        // load 64 channel rows x 32 floats (128-B coalesced segments)
#pragma unroll
        for (int pass = 0; pass < 2; ++pass) {
            int cl = pass * 32 + (t >> 3);
            f32x4 v = *(const f32x4*)&src[(size_t)(c0 + cl) * HW + s0 + l8 * 4];
            tile[cl][l8 * 4 + 0] = v[0];
            tile[cl][l8 * 4 + 1] = v[1];
            tile[cl][l8 * 4 + 2] = v[2];
            tile[cl][l8 * 4 + 3] = v[3];
        }
        __syncthreads();
        // transpose-compute: thread handles 2 chgrps of its spatial row
#pragma unroll
        for (int q = 0; q < 2; ++q) {
            int chgrp = (t & 7) * 2 + q;
            float v0 = tile[chgrp * 4 + 0][sl];
            float v1 = tile[chgrp * 4 + 1][sl];
            float v2 = tile[chgrp * 4 + 2][sl];
            float v3 = tile[chgrp * 4 + 3][sl];
            ss += v0 * v0 + v1 * v1 + v2 * v2 + v3 * v3;   // raw sum-sq
            outT[sl * 192 + cb * 16 + chgrp] =
                pk4_fp8(v0 * mult, v1 * mult, v2 * mult, v3 * mult);
        }
        __syncthreads();   // WAR fence: tile reused next cb
    }

    // reduce ss across the 8 lanes sharing a spatial row (lane bits 0..2)
#pragma unroll
    for (int m = 1; m < 8; m <<= 1) ss += __shfl_xor(ss, m, 64);
    if ((t & 7) == 0) {
        int s_idx = s0 + sl;
        sums[s_idx] = ss;                                   // plain store
        if (z) invdb[s_idx] = 1.0f / (sqrtf(ss + EPSF) + EPSF);
    }

    // store: strip output = ONE contiguous 24 KB range of dst.
    // 6 passes x 256 threads x dwordx4 = perfect 4-KB bursts.
    uint8_t* gout = dst + (size_t)s0 * CDIM;
    const uint8_t* lsrc = (const uint8_t*)outT;
#pragma unroll
    for (int p = 0; p < 6; ++p) {
        int off = p * 4096 + t * 16;
        *(u32x4*)(gout + off) = *(const u32x4*)(lsrc + off);
    }
}

// ---- Kernel 2: MX-scaled fp8 GEMM + normalize + argmax epilogue ----
// UNCHANGED (session-best, 280us, verified across 3 rounds).
// Drain-per-tile + ~44% occupancy = established optimum. 128x128 block,
// 4 waves, 64x64 wave tile, 64 VGPR + 64 AGPR. BK=64 double-buffer:
// STAGE(t+1) before COMPUTE(t), vmcnt(0) after compute + raw s_barrier.
// Swizzle involution (64B rows): write chunk (lane&3)^((lane>>3)&3),
// read key ^((l31>>1)&3). Swapped operands -> lane-local argmax.
// C/D 32x32: col=lane&31, row=(reg&3)+8*(reg>>2)+4*(lane>>5).
// Sentinels: WRITE_SIZE 33MB, conflicts 2.517e7, FETCH 204MB.
__global__ void
gemm_argmax(const uint8_t* __restrict__ at8, const uint8_t* __restrict__ bn8,
            const float* __restrict__ invdb,
            unsigned long long* __restrict__ best) {
    __shared__ uint8_t Al[2 * 8192];   // [buf][128 rows][64 B]
    __shared__ uint8_t Bl[2 * 8192];

    const int g = blockIdx.x;          // 0..16383
    const int xcd    = g & 7;
    const int s      = g >> 3;
    const int super  = s >> 5;         // 32 blocks / supertile
    const int within = s & 31;
    const int si = super >> 4;         // 4 i-tiles per supertile row
    const int sj = super & 15;         // 8 j-tiles per supertile col
    const int it = xcd * 16 + si * 4 + (within & 3);
    const int jt = sj * 8 + (within >> 2);

    const int i0 = it * 128, j0 = jt * 128;
    const int tid = threadIdx.x;
    const int lane = tid & 63, w = tid >> 6;
    const int wi = w & 1, wj = w >> 1;
    const int l31 = lane & 31, hi = lane >> 5;

    f32x16 acc[2][2] = {};   // [nj][mi]: rows j (regs), cols i (lanes)

    const int srow = lane >> 2;
    const int schunk = ((lane & 3) ^ ((lane >> 3) & 3)) * 16;
    const uint8_t* gA = at8 + (size_t)(i0 + w * 32 + srow) * CDIM + schunk;
    const uint8_t* gB = bn8 + (size_t)(j0 + w * 32 + srow) * CDIM + schunk;
    uint8_t* lA = Al + w * 2048;       // this wave's 32 rows
    uint8_t* lB = Bl + w * 2048;

    const int rA0 = (wi * 64 + l31) * 64;
    const int rB0 = (wj * 64 + l31) * 64;
    const int c0 = ((hi * 2) ^ ((l31 >> 1) & 3)) * 16;   // second b128 at ^16

#define STAGE(bo, kk)                                         \
    do {                                                      \
        async16(gA + (kk),             lA + (bo));            \
        async16(gA + (kk) + 16 * CDIM, lA + (bo) + 1024);     \
        async16(gB + (kk),             lB + (bo));            \
        async16(gB + (kk) + 16 * CDIM, lB + (bo) + 1024);     \
    } while (0)

#define COMPUTE(bo)                                                          \
    do {                                                                     \
        i32x8 af0, af1, bg;                                                  \
        *(u32x4*)&af0       = *(const u32x4*)&Al[(bo) + rA0 + c0];           \
        *((u32x4*)&af0 + 1) = *(const u32x4*)&Al[(bo) + rA0 + (c0 ^ 16)];    \
        *(u32x4*)&af1       = *(const u32x4*)&Al[(bo) + rA0 + 2048 + c0];    \
        *((u32x4*)&af1 + 1) = *(const u32x4*)&Al[(bo) + rA0 + 2048 + (c0 ^ 16)]; \
        *(u32x4*)&bg        = *(const u32x4*)&Bl[(bo) + rB0 + c0];           \
        *((u32x4*)&bg + 1)  = *(const u32x4*)&Bl[(bo) + rB0 + (c0 ^ 16)];    \
        acc[0][0] = __builtin_amdgcn_mfma_scale_f32_32x32x64_f8f6f4(         \
            bg, af0, acc[0][0], 0, 0, 0, 0x7F7F7F7F, 0, 0x7F7F7F7F);         \
        acc[0][1] = __builtin_amdgcn_mfma_scale_f32_32x32x64_f8f6f4(         \
            bg, af1, acc[0][1], 0, 0, 0, 0x7F7F7F7F, 0, 0x7F7F7F7F);         \
        *(u32x4*)&bg        = *(const u32x4*)&Bl[(bo) + rB0 + 2048 + c0];    \
        *((u32x4*)&bg + 1)  = *(const u32x4*)&Bl[(bo) + rB0 + 2048 + (c0 ^ 16)]; \
        acc[1][0] = __builtin_amdgcn_mfma_scale_f32_32x32x64_f8f6f4(         \
            bg, af0, acc[1][0], 0, 0, 0, 0x7F7F7F7F, 0, 0x7F7F7F7F);         \
        acc[1][1] = __builtin_amdgcn_mfma_scale_f32_32x32x64_f8f6f4(         \
            bg, af1, acc[1][1], 0, 0, 0, 0x7F7F7F7F, 0, 0x7F7F7F7F);         \
    } while (0)

    // prologue: stage tile 0, drain, barrier
    STAGE(0, 0);
    asm volatile("s_waitcnt vmcnt(0)" ::: "memory");
    __builtin_amdgcn_s_barrier();

#pragma unroll 1
    for (int t = 0; t < 11; ++t) {
        const int bo = (t & 1) * 8192;
        STAGE(bo ^ 8192, (t + 1) * 64);   // issue next tile (latency hides
        COMPUTE(bo);                      //   under this compute phase)
        asm volatile("s_waitcnt vmcnt(0)" ::: "memory");  // next tile landed
        __builtin_amdgcn_s_barrier();
    }
    COMPUTE(8192);                        // t=11, no further staging

#undef STAGE
#undef COMPUTE

    // epilogue: normalize by per-j inv-denom (precomputed, reg-indexed),
    // lane-local argmax over the 32 j's, one hi-exchange + atomicMax.
    float bv[2] = {-1e30f, -1e30f};
    int   bj[2] = {0, 0};
#pragma unroll
    for (int nj = 0; nj < 2; ++nj) {
        const int jb = j0 + wj * 64 + nj * 32 + 4 * hi;
        f32x4 iv[4];
#pragma unroll
        for (int q = 0; q < 4; ++q)
            iv[q] = *(const f32x4*)&invdb[jb + 8 * q];
#pragma unroll
        for (int mi = 0; mi < 2; ++mi) {
#pragma unroll
            for (int r = 0; r < 16; ++r) {
                int j = jb + (r & 3) + 8 * (r >> 2);
                float v = acc[nj][mi][r] * iv[r >> 2][r & 3];
                if (v > bv[mi] || (v == bv[mi] && j < bj[mi])) {
                    bv[mi] = v; bj[mi] = j;
                }
            }
        }
    }
#pragma unroll
    for (int mi = 0; mi < 2; ++mi) {
        float ov = __shfl_xor(bv[mi], 32, 64);
        int   oj = __shfl_xor(bj[mi], 32, 64);
        if (ov > bv[mi] || (ov == bv[mi] && oj < bj[mi])) {
            bv[mi] = ov; bj[mi] = oj;
        }
        if (hi == 0) {
            int gi = i0 + wi * 64 + mi * 32 + l31;
            uint32_t u = __float_as_uint(bv[mi]);
            u = (u & 0x80000000u) ? ~u : (u | 0x80000000u);  // orderable f32
            unsigned long long packed =
                ((unsigned long long)u << 32) | (uint32_t)(~(uint32_t)bj[mi]);
            atomicMax(&best[gi], packed);  // ties -> larger ~j -> smaller j
        }
    }
}

// ---- Kernel 3: final loss from stored argmax dot (no gather) ----
// stored v = 128 * dot(a_i, b_j) / denom_b[j]  (fp8 dot, fp32 denom)
__global__ void loss_reduce(const unsigned long long* __restrict__ best,
                            const float* __restrict__ sumsq_a,
                            const float* __restrict__ sumsq_b,
                            float* __restrict__ out) {
    int i = blockIdx.x * 256 + threadIdx.x;
    unsigned long long pk = best[i];
    uint32_t x = (uint32_t)(pk >> 32);
    float v = (x & 0x80000000u) ? __uint_as_float(x & 0x7fffffffu)
                                : __uint_as_float(~x);
    int j = (int)(~(uint32_t)pk);
    float sb = sumsq_b[j];
    float denb = sqrtf(sb + EPSF) + EPSF;
    float dot = v * denb * (1.0f / 128.0f);
    float cs = dot / ((sqrtf(sumsq_a[i]) + EPSF) * (sqrtf(sb) + EPSF));
    float term = 1.0f - cs;
#pragma unroll
    for (int m = 32; m; m >>= 1) term += __shfl_down(term, m, 64);
    __shared__ float red[4];
    int wv = threadIdx.x >> 6, lane = threadIdx.x & 63;
    if (lane == 0) red[wv] = term;
    __syncthreads();
    if (threadIdx.x == 0) {
        float ssum = (red[0] + red[1] + red[2] + red[3]) * (1.0f / HW);
        atomicAdd(out, ssum);
    }
}

extern "C" void kernel_launch(void* const* d_in, const int* in_sizes, int n_in,
                              void* d_out, int out_size, void* d_ws, size_t ws_size,
                              hipStream_t stream) {
    const float* a = (const float*)d_in[0];
    const float* b = (const float*)d_in[1];
    char* ws = (char*)d_ws;

    const size_t T_BYTES = (size_t)HW * CDIM;   // 12.58 MB per fp8 matrix
    uint8_t* at8 = (uint8_t*)ws;
    uint8_t* bn8 = (uint8_t*)(ws + T_BYTES);
    float* sumsq_a = (float*)(ws + 2 * T_BYTES);
    float* sumsq_b = (float*)(ws + 2 * T_BYTES + HW * sizeof(float));
    unsigned long long* best =
        (unsigned long long*)(ws + 2 * T_BYTES + 2 * HW * sizeof(float));
    float* invdb = (float*)(ws + 2 * T_BYTES + 2 * HW * sizeof(float)
                            + HW * sizeof(unsigned long long));

    // zero only best (+ output); sums/invdb are plain-stored by transpose
    hipMemsetAsync(best, 0, HW * sizeof(unsigned long long), stream);
    hipMemsetAsync(d_out, 0, out_size * sizeof(float), stream);

    dim3 tg(HW / 32, 1, 2);
    transpose_fp8_strip<<<tg, 256, 0, stream>>>(a, b, at8, bn8,
                                                sumsq_a, sumsq_b, invdb);
    gemm_argmax<<<(HW / 128) * (HW / 128), 256, 0, stream>>>(at8, bn8, invdb, best);
    loss_reduce<<<HW / 256, 256, 0, stream>>>(best, sumsq_a, sumsq_b, (float*)d_out);
}